// Round 1
// baseline (476.954 us; speedup 1.0000x reference)
//
#include <hip/hip_runtime.h>
#include <cstdint>
#include <cstddef>

#define NN 200000
#define DD 256
#define HH 1024
#define OUTD 4002
#define LL 2001
#define GG 4096

typedef unsigned short u16;
typedef short short8 __attribute__((ext_vector_type(8)));
typedef float f32x4 __attribute__((ext_vector_type(4)));

static __device__ __forceinline__ u16 f2bf(float f) {
  uint32_t u = __float_as_uint(f);
  uint32_t r = (u + 0x7FFFu + ((u >> 16) & 1u)) >> 16;
  return (u16)r;
}
static __device__ __forceinline__ float bf2f(u16 b) {
  return __uint_as_float(((uint32_t)b) << 16);
}

static __device__ __forceinline__ void gld_lds16(const void* g, void* l) {
  __builtin_amdgcn_global_load_lds((const __attribute__((address_space(1))) void*)g,
                                   (__attribute__((address_space(3))) void*)l,
                                   16, 0, 0);
}

// ---------------- convert fp32 -> bf16 (vectorized) ----------------
__global__ __launch_bounds__(256) void cvt_f32_bf16(const float* __restrict__ x,
                                                    u16* __restrict__ y, int n4) {
  int stride = gridDim.x * blockDim.x;
  for (int i = blockIdx.x * blockDim.x + threadIdx.x; i < n4; i += stride) {
    float4 v = reinterpret_cast<const float4*>(x)[i];
    uint32_t lo = ((uint32_t)f2bf(v.y) << 16) | (uint32_t)f2bf(v.x);
    uint32_t hi = ((uint32_t)f2bf(v.w) << 16) | (uint32_t)f2bf(v.z);
    reinterpret_cast<uint2*>(y)[i] = make_uint2(lo, hi);
  }
}

// ---------------- transpose W (K x Nc fp32) -> WT (Nc x K bf16) ----------------
__global__ __launch_bounds__(256) void transpose_bf16(const float* __restrict__ W,
                                                      u16* __restrict__ WT,
                                                      int K, int Nc) {
  __shared__ float tile[32][33];
  int nt = blockIdx.x * 32, kt = blockIdx.y * 32;
  int tx = threadIdx.x & 31, ty = threadIdx.x >> 5;  // 32 x 8
#pragma unroll
  for (int i = 0; i < 4; ++i) {
    int k = kt + ty + i * 8, n = nt + tx;
    tile[ty + i * 8][tx] = (k < K && n < Nc) ? W[(size_t)k * Nc + n] : 0.f;
  }
  __syncthreads();
#pragma unroll
  for (int i = 0; i < 4; ++i) {
    int n = nt + ty + i * 8, k = kt + tx;
    if (n < Nc && k < K) WT[(size_t)n * K + k] = f2bf(tile[tx][ty + i * 8]);
  }
}

// ---------------- per-graph row offsets via binary search ----------------
__global__ void graph_offsets(const int* __restrict__ idx, int* __restrict__ offs) {
  int g = blockIdx.x * blockDim.x + threadIdx.x;
  if (g > GG) return;
  int lo = 0, hi = NN;
  while (lo < hi) {
    int mid = (lo + hi) >> 1;
    if (idx[mid] < g) lo = mid + 1; else hi = mid;
  }
  offs[g] = lo;
}

// ---------------- fused segmented softmax pooling (online) ----------------
// h: N x 256 fp32; att: N x 256 bf16; out hG: G x 256 bf16
__global__ __launch_bounds__(128) void seg_pool(const float* __restrict__ h,
                                                const u16* __restrict__ att,
                                                const int* __restrict__ offs,
                                                u16* __restrict__ hG) {
  int g = blockIdx.x;
  int t = threadIdx.x;  // 0..127, features 2t, 2t+1
  int s = offs[g], e = offs[g + 1];
  float m0 = -INFINITY, m1 = -INFINITY;
  float s0 = 0.f, s1 = 0.f, a0acc = 0.f, a1acc = 0.f;
  for (int r = s; r < e; ++r) {
    float2 hv = *reinterpret_cast<const float2*>(&h[(size_t)r * 256 + 2 * t]);
    uint32_t ab = *reinterpret_cast<const uint32_t*>(&att[(size_t)r * 256 + 2 * t]);
    float a0 = bf2f((u16)(ab & 0xFFFFu));
    float a1 = bf2f((u16)(ab >> 16));
    float n0 = fmaxf(m0, a0);
    float r0 = __expf(m0 - n0), x0 = __expf(a0 - n0);
    s0 = s0 * r0 + x0;
    a0acc = a0acc * r0 + x0 * hv.x;
    m0 = n0;
    float n1 = fmaxf(m1, a1);
    float r1 = __expf(m1 - n1), x1 = __expf(a1 - n1);
    s1 = s1 * r1 + x1;
    a1acc = a1acc * r1 + x1 * hv.y;
    m1 = n1;
  }
  float o0 = a0acc / fmaxf(s0, 1e-12f);
  float o1 = a1acc / fmaxf(s1, 1e-12f);
  uint32_t o = ((uint32_t)f2bf(o1) << 16) | (uint32_t)f2bf(o0);
  *reinterpret_cast<uint32_t*>(&hG[(size_t)g * 256 + 2 * t]) = o;
}

// ---------------- bf16 MFMA GEMM, B^T layout (m97-style 128x128 tile) ----------------
// A: M x K bf16 row-major; BT: Nn x K bf16 row-major; C = A*B (+bias) [+silu]
// MODE 0: store bf16 to Cb (M x Nn). MODE 1: fp32 triple-write (out, imag, real).
template <int SILU, int MODE>
__global__ __launch_bounds__(256) void gemm_bt(const u16* __restrict__ A,
                                               const u16* __restrict__ BT,
                                               const float* __restrict__ bias,
                                               u16* __restrict__ Cb,
                                               float* __restrict__ Cf,
                                               float* __restrict__ Ci,
                                               float* __restrict__ Cr,
                                               int M, int Nn, int K) {
  __shared__ __align__(16) u16 As[128 * 32];
  __shared__ __align__(16) u16 Bs[128 * 32];
  const int tid = threadIdx.x;
  const int wave = tid >> 6, lane = tid & 63;
  const int wr = wave >> 1, wc = wave & 1;
  const long bm = (long)blockIdx.y * 128;
  const long bn = (long)blockIdx.x * 128;

  const f32x4 zero = {0.f, 0.f, 0.f, 0.f};
  f32x4 acc[4][4];
#pragma unroll
  for (int i = 0; i < 4; ++i)
#pragma unroll
    for (int j = 0; j < 4; ++j) acc[i][j] = zero;

  const int rg = lane >> 2;        // row within a 16-row staging group
  const int kc = (lane & 3) * 8;   // k element offset (8 bf16 = 16 B)
  const int rl = lane & 15;
  const int kk = (lane >> 4) * 8;

  for (int k0 = 0; k0 < K; k0 += 32) {
#pragma unroll
    for (int c = 0; c < 2; ++c) {
      int r = wave * 32 + c * 16;
      long rA = bm + r + rg; if (rA >= M) rA = M - 1;
      long rB = bn + r + rg; if (rB >= Nn) rB = Nn - 1;
      gld_lds16(A + rA * K + k0 + kc, &As[r * 32]);
      gld_lds16(BT + rB * K + k0 + kc, &Bs[r * 32]);
    }
    __syncthreads();
    short8 af[4], bf[4];
#pragma unroll
    for (int mi = 0; mi < 4; ++mi)
      af[mi] = *reinterpret_cast<const short8*>(&As[(wr * 64 + mi * 16 + rl) * 32 + kk]);
#pragma unroll
    for (int ni = 0; ni < 4; ++ni)
      bf[ni] = *reinterpret_cast<const short8*>(&Bs[(wc * 64 + ni * 16 + rl) * 32 + kk]);
#pragma unroll
    for (int mi = 0; mi < 4; ++mi)
#pragma unroll
      for (int ni = 0; ni < 4; ++ni)
        acc[mi][ni] = __builtin_amdgcn_mfma_f32_16x16x32_bf16(af[mi], bf[ni], acc[mi][ni], 0, 0, 0);
    __syncthreads();
  }

  // epilogue: D frag layout col = lane&15, row = (lane>>4)*4 + reg
#pragma unroll
  for (int ni = 0; ni < 4; ++ni) {
    long ccol = bn + wc * 64 + ni * 16 + (lane & 15);
    if (ccol >= Nn) continue;
    float bv = bias[ccol];
#pragma unroll
    for (int mi = 0; mi < 4; ++mi) {
#pragma unroll
      for (int reg = 0; reg < 4; ++reg) {
        long rrow = bm + wr * 64 + mi * 16 + (lane >> 4) * 4 + reg;
        if (rrow >= M) continue;
        float v = acc[mi][ni][reg] + bv;
        if (SILU) v = v / (1.f + __expf(-v));
        if (MODE == 0) {
          Cb[rrow * Nn + ccol] = f2bf(v);
        } else {
          Cf[rrow * (long)OUTD + ccol] = v;
          if (ccol < LL) Ci[rrow * (long)LL + ccol] = v;
          else           Cr[rrow * (long)LL + (ccol - LL)] = v;
        }
      }
    }
  }
}

extern "C" void kernel_launch(void* const* d_in, const int* in_sizes, int n_in,
                              void* d_out, int out_size, void* d_ws, size_t ws_size,
                              hipStream_t stream) {
  const float* h      = (const float*)d_in[0];
  const int*   idx    = (const int*)d_in[1];
  const float* W_pool = (const float*)d_in[2];
  const float* b_pool = (const float*)d_in[3];
  const float* W1     = (const float*)d_in[4];
  const float* b1     = (const float*)d_in[5];
  const float* W2     = (const float*)d_in[6];
  const float* b2     = (const float*)d_in[7];
  const float* W3     = (const float*)d_in[8];
  const float* b3     = (const float*)d_in[9];

  float* out   = (float*)d_out;
  float* out_i = out + (size_t)GG * OUTD;
  float* out_r = out_i + (size_t)GG * LL;

  char* ws = (char*)d_ws;
  size_t off = 0;
  auto alloc = [&](size_t bytes) {
    void* p = ws + off;
    off += (bytes + 255) & ~(size_t)255;
    return p;
  };
  u16* h_bf   = (u16*)alloc((size_t)NN * DD * 2);
  u16* att    = (u16*)alloc((size_t)NN * DD * 2);
  u16* WpoolT = (u16*)alloc((size_t)DD * DD * 2);
  u16* W1T    = (u16*)alloc((size_t)HH * DD * 2);
  u16* W2T    = (u16*)alloc((size_t)HH * HH * 2);
  u16* W3T    = (u16*)alloc((size_t)OUTD * HH * 2);
  u16* hG     = (u16*)alloc((size_t)GG * DD * 2);
  u16* x1     = (u16*)alloc((size_t)GG * HH * 2);
  u16* x2     = (u16*)alloc((size_t)GG * HH * 2);
  int* offs   = (int*)alloc((GG + 1) * sizeof(int));

  // 1) conversions / transposes
  cvt_f32_bf16<<<2048, 256, 0, stream>>>(h, h_bf, NN * DD / 4);
  transpose_bf16<<<dim3(8, 8), 256, 0, stream>>>(W_pool, WpoolT, DD, DD);
  transpose_bf16<<<dim3(32, 8), 256, 0, stream>>>(W1, W1T, DD, HH);
  transpose_bf16<<<dim3(32, 32), 256, 0, stream>>>(W2, W2T, HH, HH);
  transpose_bf16<<<dim3(126, 32), 256, 0, stream>>>(W3, W3T, HH, OUTD);
  graph_offsets<<<(GG + 256) / 256, 256, 0, stream>>>(idx, offs);

  // 2) att = silu(h @ W_pool + b_pool)   [M=200000, N=256, K=256]
  gemm_bt<1, 0><<<dim3(2, (NN + 127) / 128), 256, 0, stream>>>(
      h_bf, WpoolT, b_pool, att, nullptr, nullptr, nullptr, NN, DD, DD);

  // 3) segmented softmax pooling -> h_G
  seg_pool<<<GG, 128, 0, stream>>>(h, att, offs, hG);

  // 4) MLP
  gemm_bt<1, 0><<<dim3(8, 32), 256, 0, stream>>>(
      hG, W1T, b1, x1, nullptr, nullptr, nullptr, GG, HH, DD);
  gemm_bt<1, 0><<<dim3(8, 32), 256, 0, stream>>>(
      x1, W2T, b2, x2, nullptr, nullptr, nullptr, GG, HH, HH);
  gemm_bt<0, 1><<<dim3(32, 32), 256, 0, stream>>>(
      x2, W3T, b3, nullptr, out, out_i, out_r, GG, OUTD, HH);
}

// Round 2
// 360.281 us; speedup vs baseline: 1.3238x; 1.3238x over previous
//
#include <hip/hip_runtime.h>
#include <cstdint>
#include <cstddef>

#define NN 200000
#define DD 256
#define HH 1024
#define OUTD 4002
#define LL 2001
#define GG 4096

typedef unsigned short u16;
typedef short short8 __attribute__((ext_vector_type(8)));
typedef float f32x4 __attribute__((ext_vector_type(4)));

static __device__ __forceinline__ u16 f2bf(float f) {
  uint32_t u = __float_as_uint(f);
  uint32_t r = (u + 0x7FFFu + ((u >> 16) & 1u)) >> 16;
  return (u16)r;
}
static __device__ __forceinline__ float bf2f(u16 b) {
  return __uint_as_float(((uint32_t)b) << 16);
}

static __device__ __forceinline__ void gld_lds16(const void* g, void* l) {
  __builtin_amdgcn_global_load_lds((const __attribute__((address_space(1))) void*)g,
                                   (__attribute__((address_space(3))) void*)l,
                                   16, 0, 0);
}

// ---------------- transpose W (K x Nc fp32) -> WT (Nc x K bf16) ----------------
__global__ __launch_bounds__(256) void transpose_bf16(const float* __restrict__ W,
                                                      u16* __restrict__ WT,
                                                      int K, int Nc) {
  __shared__ float tile[32][33];
  int nt = blockIdx.x * 32, kt = blockIdx.y * 32;
  int tx = threadIdx.x & 31, ty = threadIdx.x >> 5;  // 32 x 8
#pragma unroll
  for (int i = 0; i < 4; ++i) {
    int k = kt + ty + i * 8, n = nt + tx;
    tile[ty + i * 8][tx] = (k < K && n < Nc) ? W[(size_t)k * Nc + n] : 0.f;
  }
  __syncthreads();
#pragma unroll
  for (int i = 0; i < 4; ++i) {
    int n = nt + ty + i * 8, k = kt + tx;
    if (n < Nc && k < K) WT[(size_t)n * K + k] = f2bf(tile[tx][ty + i * 8]);
  }
}

// ---------------- per-graph row offsets via binary search ----------------
__global__ void graph_offsets(const int* __restrict__ idx, int* __restrict__ offs) {
  int g = blockIdx.x * blockDim.x + threadIdx.x;
  if (g > GG) return;
  int lo = 0, hi = NN;
  while (lo < hi) {
    int mid = (lo + hi) >> 1;
    if (idx[mid] < g) lo = mid + 1; else hi = mid;
  }
  offs[g] = lo;
}

// ---------------- fused: att-GEMM + segmented online softmax pooling ----------------
// One block per graph. h read ONCE (fp32). W_pool^T hoisted to registers.
// att never materialized. Output hG: G x 256 bf16.
__global__ __launch_bounds__(512) void fused_pool(const float* __restrict__ h,
                                                  const u16* __restrict__ WT,
                                                  const float* __restrict__ bias,
                                                  const int* __restrict__ offs,
                                                  u16* __restrict__ hG) {
  __shared__ __align__(16) u16 At[2][16 * 256];  // 16 rows x 256 feats, XOR-swizzled
  const int tid = threadIdx.x;
  const int wave = tid >> 6, lane = tid & 63;
  const int rl = lane & 15, q = lane >> 4;
  const int g = blockIdx.x;
  const int s = offs[g], e = offs[g + 1];
  const int cnt = e - s;

  // Hoist B-frags from global (L2-resident 128 KB): feature = wave*32 + t*16 + rl
  short8 Bf[2][8];
#pragma unroll
  for (int t = 0; t < 2; ++t) {
    const u16* wp = WT + (size_t)(wave * 32 + t * 16 + rl) * 256 + q * 8;
#pragma unroll
    for (int k0 = 0; k0 < 8; ++k0)
      Bf[t][k0] = *reinterpret_cast<const short8*>(wp + k0 * 32);
  }
  float bv[2] = {bias[wave * 32 + rl], bias[wave * 32 + 16 + rl]};

  // per-lane online softmax state for 2 features (rows subset q*4+reg per step)
  float m[2] = {-1e30f, -1e30f}, ss[2] = {0.f, 0.f}, ah[2] = {0.f, 0.f};

  const int nsteps = (cnt + 15) >> 4;
  // staging: thread -> row tr = tid>>5 (0..15), elems te..te+7
  const int tr = tid >> 5, te = (tid & 31) * 8;
  const int wbyte = tr * 512 + ((te * 2) ^ ((tr & 7) << 4));
  float4 pf0, pf1;
  auto issue = [&](int st) {
    long r = (long)s + (long)st * 16 + tr;
    if (r >= NN) r = NN - 1;
    const float* p = h + r * 256 + te;
    pf0 = *reinterpret_cast<const float4*>(p);
    pf1 = *reinterpret_cast<const float4*>(p + 4);
  };

  if (nsteps > 0) issue(0);
  for (int st = 0; st < nsteps; ++st) {
    const int buf = st & 1;
    // commit prefetched rows -> LDS (bf16, swizzled)
    short8 w;
    w[0] = (short)f2bf(pf0.x); w[1] = (short)f2bf(pf0.y);
    w[2] = (short)f2bf(pf0.z); w[3] = (short)f2bf(pf0.w);
    w[4] = (short)f2bf(pf1.x); w[5] = (short)f2bf(pf1.y);
    w[6] = (short)f2bf(pf1.z); w[7] = (short)f2bf(pf1.w);
    *reinterpret_cast<short8*>((char*)&At[buf][0] + wbyte) = w;
    if (st + 1 < nsteps) issue(st + 1);
    __syncthreads();

    // A-frags: row = rl, k = k0*32 + q*8
    short8 af[8];
#pragma unroll
    for (int k0 = 0; k0 < 8; ++k0) {
      int byt = rl * 512 + (((k0 * 32 + q * 8) * 2) ^ ((rl & 7) << 4));
      af[k0] = *reinterpret_cast<const short8*>((const char*)&At[buf][0] + byt);
    }
#pragma unroll
    for (int t = 0; t < 2; ++t) {
      f32x4 acc = {0.f, 0.f, 0.f, 0.f};
#pragma unroll
      for (int k0 = 0; k0 < 8; ++k0)
        acc = __builtin_amdgcn_mfma_f32_16x16x32_bf16(af[k0], Bf[t][k0], acc, 0, 0, 0);
      const int fl = wave * 32 + t * 16 + rl;
#pragma unroll
      for (int reg = 0; reg < 4; ++reg) {
        int rloc = q * 4 + reg;
        float z = acc[reg] + bv[t];
        float a = z / (1.f + __expf(-z));  // silu(z) -> att value
        int hb = rloc * 512 + ((fl * 2) ^ ((rloc & 7) << 4));
        float hv = bf2f(*reinterpret_cast<const u16*>((const char*)&At[buf][0] + hb));
        bool valid = (st * 16 + rloc) < cnt;
        float n = valid ? fmaxf(m[t], a) : m[t];
        float sc = __expf(m[t] - n);
        float x = valid ? __expf(a - n) : 0.f;
        ss[t] = ss[t] * sc + x;
        ah[t] = ah[t] * sc + x * hv;
        m[t] = n;
      }
    }
    __syncthreads();
  }

  // merge partial softmax states across the 4 quarter-lanes (xor 16, 32)
#pragma unroll
  for (int t = 0; t < 2; ++t) {
#pragma unroll
    for (int d = 16; d <= 32; d <<= 1) {
      float mo = __shfl_xor(m[t], d);
      float so = __shfl_xor(ss[t], d);
      float ao = __shfl_xor(ah[t], d);
      float n = fmaxf(m[t], mo);
      float e1 = __expf(m[t] - n), e2 = __expf(mo - n);
      ss[t] = ss[t] * e1 + so * e2;
      ah[t] = ah[t] * e1 + ao * e2;
      m[t] = n;
    }
  }
  if (q == 0) {
#pragma unroll
    for (int t = 0; t < 2; ++t) {
      float o = ah[t] / fmaxf(ss[t], 1e-12f);
      hG[(size_t)g * 256 + wave * 32 + t * 16 + rl] = f2bf(o);
    }
  }
}

// ---------------- bf16 MFMA GEMM, B^T layout (m97-style 128x128 tile) ----------------
template <int SILU, int MODE>
__global__ __launch_bounds__(256) void gemm_bt(const u16* __restrict__ A,
                                               const u16* __restrict__ BT,
                                               const float* __restrict__ bias,
                                               u16* __restrict__ Cb,
                                               float* __restrict__ Cf,
                                               float* __restrict__ Ci,
                                               float* __restrict__ Cr,
                                               int M, int Nn, int K) {
  __shared__ __align__(16) u16 As[128 * 32];
  __shared__ __align__(16) u16 Bs[128 * 32];
  const int tid = threadIdx.x;
  const int wave = tid >> 6, lane = tid & 63;
  const int wr = wave >> 1, wc = wave & 1;
  const long bm = (long)blockIdx.y * 128;
  const long bn = (long)blockIdx.x * 128;

  const f32x4 zero = {0.f, 0.f, 0.f, 0.f};
  f32x4 acc[4][4];
#pragma unroll
  for (int i = 0; i < 4; ++i)
#pragma unroll
    for (int j = 0; j < 4; ++j) acc[i][j] = zero;

  const int rg = lane >> 2;
  const int kc = (lane & 3) * 8;
  const int rl = lane & 15;
  const int kk = (lane >> 4) * 8;

  for (int k0 = 0; k0 < K; k0 += 32) {
#pragma unroll
    for (int c = 0; c < 2; ++c) {
      int r = wave * 32 + c * 16;
      long rA = bm + r + rg; if (rA >= M) rA = M - 1;
      long rB = bn + r + rg; if (rB >= Nn) rB = Nn - 1;
      gld_lds16(A + rA * K + k0 + kc, &As[r * 32]);
      gld_lds16(BT + rB * K + k0 + kc, &Bs[r * 32]);
    }
    __syncthreads();
    short8 af[4], bf[4];
#pragma unroll
    for (int mi = 0; mi < 4; ++mi)
      af[mi] = *reinterpret_cast<const short8*>(&As[(wr * 64 + mi * 16 + rl) * 32 + kk]);
#pragma unroll
    for (int ni = 0; ni < 4; ++ni)
      bf[ni] = *reinterpret_cast<const short8*>(&Bs[(wc * 64 + ni * 16 + rl) * 32 + kk]);
#pragma unroll
    for (int mi = 0; mi < 4; ++mi)
#pragma unroll
      for (int ni = 0; ni < 4; ++ni)
        acc[mi][ni] = __builtin_amdgcn_mfma_f32_16x16x32_bf16(af[mi], bf[ni], acc[mi][ni], 0, 0, 0);
    __syncthreads();
  }

#pragma unroll
  for (int ni = 0; ni < 4; ++ni) {
    long ccol = bn + wc * 64 + ni * 16 + (lane & 15);
    if (ccol >= Nn) continue;
    float bv = bias[ccol];
#pragma unroll
    for (int mi = 0; mi < 4; ++mi) {
#pragma unroll
      for (int reg = 0; reg < 4; ++reg) {
        long rrow = bm + wr * 64 + mi * 16 + (lane >> 4) * 4 + reg;
        if (rrow >= M) continue;
        float v = acc[mi][ni][reg] + bv;
        if (SILU) v = v / (1.f + __expf(-v));
        if (MODE == 0) {
          Cb[rrow * Nn + ccol] = f2bf(v);
        } else {
          Cf[rrow * (long)OUTD + ccol] = v;
          if (ccol < LL) Ci[rrow * (long)LL + ccol] = v;
          else           Cr[rrow * (long)LL + (ccol - LL)] = v;
        }
      }
    }
  }
}

extern "C" void kernel_launch(void* const* d_in, const int* in_sizes, int n_in,
                              void* d_out, int out_size, void* d_ws, size_t ws_size,
                              hipStream_t stream) {
  const float* h      = (const float*)d_in[0];
  const int*   idx    = (const int*)d_in[1];
  const float* W_pool = (const float*)d_in[2];
  const float* b_pool = (const float*)d_in[3];
  const float* W1     = (const float*)d_in[4];
  const float* b1     = (const float*)d_in[5];
  const float* W2     = (const float*)d_in[6];
  const float* b2     = (const float*)d_in[7];
  const float* W3     = (const float*)d_in[8];
  const float* b3     = (const float*)d_in[9];

  float* out   = (float*)d_out;
  float* out_i = out + (size_t)GG * OUTD;
  float* out_r = out_i + (size_t)GG * LL;

  char* ws = (char*)d_ws;
  size_t off = 0;
  auto alloc = [&](size_t bytes) {
    void* p = ws + off;
    off += (bytes + 255) & ~(size_t)255;
    return p;
  };
  u16* WpoolT = (u16*)alloc((size_t)DD * DD * 2);
  u16* W1T    = (u16*)alloc((size_t)HH * DD * 2);
  u16* W2T    = (u16*)alloc((size_t)HH * HH * 2);
  u16* W3T    = (u16*)alloc((size_t)OUTD * HH * 2);
  u16* hG     = (u16*)alloc((size_t)GG * DD * 2);
  u16* x1     = (u16*)alloc((size_t)GG * HH * 2);
  u16* x2     = (u16*)alloc((size_t)GG * HH * 2);
  int* offs   = (int*)alloc((GG + 1) * sizeof(int));

  // 1) weight transposes + graph offsets
  transpose_bf16<<<dim3(8, 8), 256, 0, stream>>>(W_pool, WpoolT, DD, DD);
  transpose_bf16<<<dim3(32, 8), 256, 0, stream>>>(W1, W1T, DD, HH);
  transpose_bf16<<<dim3(32, 32), 256, 0, stream>>>(W2, W2T, HH, HH);
  transpose_bf16<<<dim3(126, 32), 256, 0, stream>>>(W3, W3T, HH, OUTD);
  graph_offsets<<<(GG + 256) / 256, 256, 0, stream>>>(idx, offs);

  // 2) fused att-GEMM + segmented softmax pooling -> h_G (reads h once)
  fused_pool<<<GG, 512, 0, stream>>>(h, WpoolT, b_pool, offs, hG);

  // 3) MLP
  gemm_bt<1, 0><<<dim3(8, 32), 256, 0, stream>>>(
      hG, W1T, b1, x1, nullptr, nullptr, nullptr, GG, HH, DD);
  gemm_bt<1, 0><<<dim3(8, 32), 256, 0, stream>>>(
      x1, W2T, b2, x2, nullptr, nullptr, nullptr, GG, HH, HH);
  gemm_bt<0, 1><<<dim3(32, 32), 256, 0, stream>>>(
      x2, W3T, b3, nullptr, out, out_i, out_r, GG, OUTD, HH);
}